// Round 10
// baseline (118.057 us; speedup 1.0000x reference)
//
#include <hip/hip_runtime.h>
#include <math.h>

// MovingMaxMinHorizontal: causal max-filter(L=64) then min-filter(L=64) over
// [B=64, C=64, T=4096] f32 rows with -inf / +inf streaming-state left pads.
//
// Round-8: stage 1 reads x directly from global (4B-aligned dwordx4), no s_in
// staging, no staging barrier. Boundary slabs (head = prev_input pad, tail =
// last slab with -inf slot) are composed in the consuming lanes' registers.
// Only s_mid (mpad) lives in LDS; ONE __syncthreads in the whole kernel.
//
// Scan structure (verified, round 7): 256 outputs per wave-chunk, 4 elems/lane,
// one 64-slab per 16-lane DPP row. out[t] = OP(suffix(a0)[t], excl_prefix(a1)[t])
// via within-lane serial scans (3 ops) + row scans of lane totals with DPP
// row_shl/row_shr 1,2,4,8. Stage-1 writeback realigned in-register:
// w3 = update_dpp(old=u, src=r0, row_shl:1); at row-boundary lanes the needed
// value IS the a1-slab total u.

#define TT   4096
#define PADN 63
#define SLEN 4160

// 4-byte-aligned float4 for unaligned-by-one global vector loads.
struct __attribute__((packed, aligned(4))) f4u { float x, y, z, w; };

template<int CTRL>
__device__ __forceinline__ float dpp_self(float v) {
  return __int_as_float(__builtin_amdgcn_update_dpp(
      __float_as_int(v), __float_as_int(v), CTRL, 0xF, 0xF, false));
}
template<int CTRL>
__device__ __forceinline__ float dpp_old(float oldv, float v) {
  return __int_as_float(__builtin_amdgcn_update_dpp(
      __float_as_int(oldv), __float_as_int(v), CTRL, 0xF, 0xF, false));
}

// Window results r[0..3] for this lane from slabs a0 (own) / a1 (next);
// u_out = inclusive row-prefix of a1 lane-totals.
template<bool IS_MAX>
__device__ __forceinline__ void chunk_windows(float4 a0, float4 a1, int lane,
                                              float r[4], float& u_out) {
  const float ID = IS_MAX ? -INFINITY : INFINITY;
#define OPF(x, y) (IS_MAX ? fmaxf((x), (y)) : fminf((x), (y)))
  // within-lane suffix scan of a0
  float s3 = a0.w;
  float s2 = OPF(a0.z, s3);
  float s1 = OPF(a0.y, s2);
  float s0 = OPF(a0.x, s1);
  // row-level inclusive suffix scan of lane totals (row_shl:d = lane i <- i+d)
  float t = s0;
  t = OPF(t, dpp_self<0x101>(t));
  t = OPF(t, dpp_self<0x102>(t));
  t = OPF(t, dpp_self<0x104>(t));
  t = OPF(t, dpp_self<0x108>(t));
  float E = dpp_old<0x101>(ID, t);   // exclusive lane-suffix (lane15 of row -> ID)

  // within-lane prefix scan of a1
  float p0 = a1.x;
  float p1 = OPF(p0, a1.y);
  float p2 = OPF(p1, a1.z);
  float p3 = OPF(p2, a1.w);
  float u = p3;
  u = OPF(u, dpp_self<0x111>(u));    // row_shr:d = lane i <- i-d
  u = OPF(u, dpp_self<0x112>(u));
  u = OPF(u, dpp_self<0x114>(u));
  u = OPF(u, dpp_self<0x118>(u));
  float Ep = dpp_old<0x111>(ID, u);  // exclusive lane-prefix (lane0 of row -> ID)

  r[0] = OPF(OPF(s0, E), Ep);
  r[1] = OPF(OPF(s1, E), OPF(Ep, p0));
  r[2] = OPF(OPF(s2, E), OPF(Ep, p1));
  r[3] = OPF(OPF(s3, E), OPF(Ep, p2));
  u_out = u;
#undef OPF
}

__global__ __launch_bounds__(512)
void mmh_kernel(const float* __restrict__ x,
                const float* __restrict__ prev_input,
                const float* __restrict__ prev_max_out,
                float* __restrict__ out)
{
    __shared__ float s_mid[SLEN];   // mpad[p]: [prev_max_out(63), mid(4096), 1 slack]

    const int row  = blockIdx.x;
    const int tid  = threadIdx.x;
    const int lane = tid & 63;
    const int wave = tid >> 6;      // 0..7

    const float* xrow  = x            + (size_t)row * TT;
    const float* pirow = prev_input   + (size_t)row * PADN;
    const float* pmrow = prev_max_out + (size_t)row * PADN;
    float*       orow  = out          + (size_t)row * TT;

    // mpad head: prev_max_out (disjoint from stage-1 writes; before the barrier)
    if (tid < PADN) s_mid[tid] = pmrow[tid];

    // ---- stage 1: sliding max over xpad -> s_mid (global-direct reads) ----
    #pragma unroll
    for (int cc = 0; cc < 2; ++cc) {
        const int b = (wave + 8 * cc) << 8;   // padded-coord slab base
        float4 a0, a1;
        // a0 = xpad[b+4*lane .. +3] = x[b+4*lane-63 ...]
        if (b == 0 && lane < 16) {
            const int p = 4 * lane;           // xpad head from prev_input
            a0.x = pirow[p];
            a0.y = pirow[p + 1];
            a0.z = pirow[p + 2];
            a0.w = (lane == 15) ? xrow[0] : pirow[p + 3];
        } else {
            f4u v = *reinterpret_cast<const f4u*>(xrow + b + 4 * lane - 63);
            a0 = make_float4(v.x, v.y, v.z, v.w);
        }
        // a1 = xpad[b+64+4*lane .. +3] = x[b+4*lane+1 ...]
        if (b == 3840 && lane >= 48) {
            const int p = 4033 + 4 * (lane - 48);  // row tail, -inf identity slot
            a1.x = xrow[p];
            a1.y = xrow[p + 1];
            a1.z = xrow[p + 2];
            a1.w = (lane == 63) ? -INFINITY : xrow[p + 3];
        } else {
            f4u v = *reinterpret_cast<const f4u*>(xrow + b + 4 * lane + 1);
            a1 = make_float4(v.x, v.y, v.z, v.w);
        }

        float r[4], u;
        chunk_windows<true>(a0, a1, lane, r, u);
        // aligned b128 write of mpad[64+b+4*lane .. +3]; w3 = next lane's r0
        // (row_shl:1); at row-boundary lanes the needed value == u.
        float  w3 = dpp_old<0x101>(u, r[0]);
        float4 wv = make_float4(r[1], r[2], r[3], w3);
        *reinterpret_cast<float4*>(&s_mid[64 + b + 4 * lane]) = wv;
        if ((b | lane) == 0) s_mid[63] = r[0];   // mid[0]
    }
    __syncthreads();

    // ---- stage 2: sliding min over mpad -> out (aligned global float4) ----
    #pragma unroll
    for (int cc = 0; cc < 2; ++cc) {
        const int b = (wave + 8 * cc) << 8;
        float4 a0 = *reinterpret_cast<const float4*>(&s_mid[b + 4 * lane]);
        float4 a1 = *reinterpret_cast<const float4*>(&s_mid[b + 64 + 4 * lane]);
        float r[4], u;
        chunk_windows<false>(a0, a1, lane, r, u);
        *reinterpret_cast<float4*>(orow + b + 4 * lane) =
            make_float4(r[0], r[1], r[2], r[3]);
    }
}

extern "C" void kernel_launch(void* const* d_in, const int* in_sizes, int n_in,
                              void* d_out, int out_size, void* d_ws, size_t ws_size,
                              hipStream_t stream) {
    const float* x            = (const float*)d_in[0];  // [64,64,4096]
    const float* prev_input   = (const float*)d_in[1];  // [64,64,63]
    const float* prev_max_out = (const float*)d_in[2];  // [64,64,63]
    float*       out          = (float*)d_out;          // [64,64,4096]

    mmh_kernel<<<64 * 64, 512, 0, stream>>>(x, prev_input, prev_max_out, out);
}